// Round 4
// baseline (417.984 us; speedup 1.0000x reference)
//
#include <hip/hip_runtime.h>

typedef float f32x4 __attribute__((ext_vector_type(4)));

// Problem: B=2, L=1024, D_MODEL=512, D_INNER=1024, H=8, HD=128, N=16,
// DT_RANK=32, OUT_DIM=560, T=2048. All inputs/outputs f32.

// ---------------- workspace layout (bytes), packed ----------------
static constexpr size_t OFF_XZ    = 0;          // f32 [2048][2048] 16,777,216 (xp|z; xp half reused for yg)
static constexpr size_t OFF_XC    = 16777216;   // f32 [2048][1024]  8,388,608
static constexpr size_t OFF_PROJ  = 25165824;   // f32 [2048][560]   4,587,520
static constexpr size_t OFF_DELTA = 29753344;   // f32 [2048][1024]  8,388,608
static constexpr size_t OFF_GL    = 38141952;   // f32 [2048][8]        65,536
static constexpr size_t OFF_GE    = 38207488;   // f32 [2048][8]        65,536
static constexpr size_t OFF_SUMM  = 38273024;   // f32x4 [2][8][16][2048] 8,388,608
static constexpr size_t WS_NEEDED = 46661632;   // 44.5 MB (proven available >= 48.5 MB)

__global__ void zero_out_kernel(float* __restrict__ p, int n)
{
    int i = blockIdx.x * 256 + threadIdx.x;
    if (i < n) p[i] = 0.f;
}

// ---------------- plain f32 NT GEMM: C[M,N] = A[M,K] * B[N,K]^T -------------
// 64x64 tile, k-slice 16 in LDS (stored [k][m] for float4 compute reads),
// 256 threads, 4x4 acc each. No MFMA, no bf16 — correct by construction.
__launch_bounds__(256)
__global__ void gemm_f32(const float* __restrict__ A, const float* __restrict__ B,
                         float* __restrict__ C,
                         int M, int N, int K, int lda, int ldc)
{
    __shared__ float As[16][68];   // [k][m], pad 64->68 keeps float4 align + banks spread
    __shared__ float Bs[16][68];   // [k][n]
    const int tid = threadIdx.x;
    const int tx = tid & 15, ty = tid >> 4;
    const int m0 = blockIdx.y * 64, n0 = blockIdx.x * 64;
    const int kg = tid & 3, mr = tid >> 2;       // staging: 4 k-groups x 64 rows

    float acc[4][4] = {};

    for (int kt = 0; kt < K; kt += 16) {
        if (kt) __syncthreads();
        float4 av = *(const float4*)(A + (size_t)(m0 + mr) * lda + kt + kg * 4);
        float4 bv = make_float4(0.f, 0.f, 0.f, 0.f);
        if (n0 + mr < N)
            bv = *(const float4*)(B + (size_t)(n0 + mr) * K + kt + kg * 4);
        As[kg * 4 + 0][mr] = av.x; As[kg * 4 + 1][mr] = av.y;
        As[kg * 4 + 2][mr] = av.z; As[kg * 4 + 3][mr] = av.w;
        Bs[kg * 4 + 0][mr] = bv.x; Bs[kg * 4 + 1][mr] = bv.y;
        Bs[kg * 4 + 2][mr] = bv.z; Bs[kg * 4 + 3][mr] = bv.w;
        __syncthreads();

#pragma unroll
        for (int k = 0; k < 16; ++k) {
            float4 a = *(const float4*)&As[k][ty * 4];
            float4 b = *(const float4*)&Bs[k][tx * 4];
            acc[0][0] += a.x * b.x; acc[0][1] += a.x * b.y;
            acc[0][2] += a.x * b.z; acc[0][3] += a.x * b.w;
            acc[1][0] += a.y * b.x; acc[1][1] += a.y * b.y;
            acc[1][2] += a.y * b.z; acc[1][3] += a.y * b.w;
            acc[2][0] += a.z * b.x; acc[2][1] += a.z * b.y;
            acc[2][2] += a.z * b.z; acc[2][3] += a.z * b.w;
            acc[3][0] += a.w * b.x; acc[3][1] += a.w * b.y;
            acc[3][2] += a.w * b.z; acc[3][3] += a.w * b.w;
        }
    }

#pragma unroll
    for (int i = 0; i < 4; ++i) {
        int row = m0 + ty * 4 + i;
#pragma unroll
        for (int j = 0; j < 4; ++j) {
            int col = n0 + tx * 4 + j;
            if (col < N) C[(size_t)row * ldc + col] = acc[i][j];
        }
    }
}

// ---------------- causal depthwise conv3 + bias + silu ----------------
__global__ void conv_silu_kernel(const float* __restrict__ xz,
                                 const float* __restrict__ cw,
                                 const float* __restrict__ cb,
                                 float* __restrict__ xc)
{
    int idx = blockIdx.x * 256 + threadIdx.x;      // 2048*1024
    int t = idx >> 10, c = idx & 1023;
    int l = t & 1023;
    float w0 = cw[c * 3 + 0], w1 = cw[c * 3 + 1], w2 = cw[c * 3 + 2];
    float acc = cb[c];
    acc += w2 * xz[(size_t)t * 2048 + c];
    if (l >= 1) acc += w1 * xz[(size_t)(t - 1) * 2048 + c];
    if (l >= 2) acc += w0 * xz[(size_t)(t - 2) * 2048 + c];
    xc[idx] = acc / (1.f + __expf(-acc));          // silu
}

// ---------------- delta = softplus(delta_raw @ Wdt^T + b); gate sigmoids ----
__global__ void dt_kernel(const float* __restrict__ proj,
                          const float* __restrict__ Wdt, const float* __restrict__ bdt,
                          float* __restrict__ delta,
                          float* __restrict__ gl, float* __restrict__ ge)
{
    int t = blockIdx.x;
    int d = blockIdx.y * 256 + threadIdx.x;
    __shared__ float pr[32];
    if (threadIdx.x < 32) pr[threadIdx.x] = proj[(size_t)t * 560 + threadIdx.x];
    __syncthreads();
    float acc = bdt[d];
    const float4* wp = (const float4*)(Wdt + (size_t)d * 32);
#pragma unroll
    for (int cc = 0; cc < 8; ++cc) {
        float4 w = wp[cc];
        acc += pr[cc * 4 + 0] * w.x + pr[cc * 4 + 1] * w.y
             + pr[cc * 4 + 2] * w.z + pr[cc * 4 + 3] * w.w;
    }
    float sp = (acc > 20.f) ? acc : log1pf(__expf(acc));
    delta[(size_t)t * 1024 + d] = sp;
    if (blockIdx.y == 0 && threadIdx.x < 8) {
        int h = threadIdx.x;
        float lgr = proj[(size_t)t * 560 + 544 + h];
        float egr = proj[(size_t)t * 560 + 552 + h];
        gl[t * 8 + h] = 1.f / (1.f + __expf(-lgr));
        ge[t * 8 + h] = 1.f / (1.f + __expf(-egr));
    }
}

// ---------------- chunked scan, pass 1: per-chunk (prod alpha, local h) -----
// grid bid -> c(16)|hdg(4)|h(8)|b(2). 512 thr: n=lane&15, hd=hdg*32+wave*4+(lane>>4)
__launch_bounds__(512)
__global__ void scan_pass1(const float* __restrict__ delta, const float* __restrict__ xc,
                           const float* __restrict__ proj,
                           const float* __restrict__ gl, const float* __restrict__ ge,
                           const float* __restrict__ Alog, const float* __restrict__ Aimg,
                           float* __restrict__ summ)
{
    const int bid = blockIdx.x;
    const int c = bid & 15, hdg = (bid >> 4) & 3, h = (bid >> 6) & 7, b = bid >> 9;
    const int tid = threadIdx.x, lane = tid & 63, wave = tid >> 6;
    const int n = lane & 15, hd = hdg * 32 + wave * 4 + (lane >> 4);
    const int di = h * 128 + hd;
    const float Ar = -__expf(Alog[h * 16 + n]);
    const float Ai = Aimg[h * 16 + n];
    const int l0 = c * 64;

    float Bxpr = 0.f, Bxpi = 0.f;
    if (c > 0) {
        int tp = b * 1024 + l0 - 1;
        float xcv = xc[(size_t)tp * 1024 + di];
        Bxpr = xcv * proj[(size_t)tp * 560 + 32 + h * 16 + n];
        Bxpi = xcv * proj[(size_t)tp * 560 + 160 + h * 16 + n];
    }
    float hr = 0.f, hi = 0.f, Pr = 1.f, Pi = 0.f;
    for (int l = l0; l < l0 + 64; ++l) {
        int t = b * 1024 + l;
        float dv  = delta[(size_t)t * 1024 + di];
        float xcv = xc[(size_t)t * 1024 + di];
        float Bre = proj[(size_t)t * 560 + 32 + h * 16 + n];
        float Bim = proj[(size_t)t * 560 + 160 + h * 16 + n];
        float lgv = gl[t * 8 + h], egv = ge[t * 8 + h];
        float dtAr = fminf(fmaxf(dv * Ar, -20.f), 20.f);
        float er = __expf(dtAr);
        float sn, cs; __sincosf(dv * Ai, &sn, &cs);
        float ar = er * cs, ai = er * sn;
        float Bxr = xcv * Bre, Bxi = xcv * Bim;
        float bs = (1.f - lgv) * dv, gm = lgv * egv * dv;
        float ur = bs * (ar * Bxpr - ai * Bxpi) + gm * Bxr;
        float ui = bs * (ar * Bxpi + ai * Bxpr) + gm * Bxi;
        float nhr = ar * hr - ai * hi + ur;
        float nhi = ar * hi + ai * hr + ui;
        hr = nhr; hi = nhi;
        float nPr = ar * Pr - ai * Pi;
        float nPi = ar * Pi + ai * Pr;
        Pr = nPr; Pi = nPi;
        Bxpr = Bxr; Bxpi = Bxi;
    }
    size_t sidx = ((size_t)((b * 8 + h) * 16 + c) * 2048 + hd * 16 + n);
    f32x4 s = {Pr, Pi, hr, hi};
    *(f32x4*)(summ + sidx * 4) = s;
}

// -------- combine: scan 16 chunk summaries per channel; init written in-place ----
__global__ void scan_combine(float* __restrict__ summ)
{
    int ch = blockIdx.x * 256 + threadIdx.x;      // 32768 channels
    int n = ch & 15, hd = (ch >> 4) & 127, bh = ch >> 11;
    float hr = 0.f, hi = 0.f;
    for (int c = 0; c < 16; ++c) {
        size_t sidx = ((size_t)(bh * 16 + c) * 2048 + hd * 16 + n);
        f32x4 s = *(const f32x4*)(summ + sidx * 4);
        summ[sidx * 4 + 0] = hr;   // overwrite (Pr,Pi) with init state entering chunk c
        summ[sidx * 4 + 1] = hi;
        float nhr = s.x * hr - s.y * hi + s.z;
        float nhi = s.x * hi + s.y * hr + s.w;
        hr = nhr; hi = nhi;
    }
}

// ---- pass 2: recompute with init state; write gated y into xz's xp half ----
// xzrw: read z at [t][1024+di], write yg at [t][di] (disjoint halves, same kernel).
__launch_bounds__(512)
__global__ void scan_pass2(const float* __restrict__ delta, const float* __restrict__ xc,
                           const float* __restrict__ proj,
                           const float* __restrict__ gl, const float* __restrict__ ge,
                           const float* __restrict__ Alog, const float* __restrict__ Aimg,
                           const float* __restrict__ Dp, float* xzrw,
                           const float* __restrict__ summ)
{
    const int bid = blockIdx.x;
    const int c = bid & 15, hdg = (bid >> 4) & 3, h = (bid >> 6) & 7, b = bid >> 9;
    const int tid = threadIdx.x, lane = tid & 63, wave = tid >> 6;
    const int n = lane & 15, hd = hdg * 32 + wave * 4 + (lane >> 4);
    const int di = h * 128 + hd;
    const float Ar = -__expf(Alog[h * 16 + n]);
    const float Ai = Aimg[h * 16 + n];
    const float Dv = Dp[di];
    const int l0 = c * 64;

    size_t sidx = ((size_t)((b * 8 + h) * 16 + c) * 2048 + hd * 16 + n);
    float hr = summ[sidx * 4 + 0], hi = summ[sidx * 4 + 1];

    float Bxpr = 0.f, Bxpi = 0.f;
    if (c > 0) {
        int tp = b * 1024 + l0 - 1;
        float xcv = xc[(size_t)tp * 1024 + di];
        Bxpr = xcv * proj[(size_t)tp * 560 + 32 + h * 16 + n];
        Bxpi = xcv * proj[(size_t)tp * 560 + 160 + h * 16 + n];
    }
    for (int l = l0; l < l0 + 64; ++l) {
        int t = b * 1024 + l;
        float dv  = delta[(size_t)t * 1024 + di];
        float xcv = xc[(size_t)t * 1024 + di];
        float Bre = proj[(size_t)t * 560 + 32 + h * 16 + n];
        float Bim = proj[(size_t)t * 560 + 160 + h * 16 + n];
        float Cre = proj[(size_t)t * 560 + 288 + h * 16 + n];
        float Cim = proj[(size_t)t * 560 + 416 + h * 16 + n];
        float lgv = gl[t * 8 + h], egv = ge[t * 8 + h];
        float dtAr = fminf(fmaxf(dv * Ar, -20.f), 20.f);
        float er = __expf(dtAr);
        float sn, cs; __sincosf(dv * Ai, &sn, &cs);
        float ar = er * cs, ai = er * sn;
        float Bxr = xcv * Bre, Bxi = xcv * Bim;
        float bs = (1.f - lgv) * dv, gm = lgv * egv * dv;
        float ur = bs * (ar * Bxpr - ai * Bxpi) + gm * Bxr;
        float ui = bs * (ar * Bxpi + ai * Bxpr) + gm * Bxi;
        float nhr = ar * hr - ai * hi + ur;
        float nhi = ar * hi + ai * hr + ui;
        hr = nhr; hi = nhi;
        Bxpr = Bxr; Bxpi = Bxi;
        float y = hr * Cre + hi * Cim;
        y += __shfl_xor(y, 1, 64);
        y += __shfl_xor(y, 2, 64);
        y += __shfl_xor(y, 4, 64);
        y += __shfl_xor(y, 8, 64);
        if (n == 0) {
            float yf = y + Dv * xcv;
            float zv = xzrw[(size_t)t * 2048 + 1024 + di];
            float g  = yf * (zv / (1.f + __expf(-zv)));
            xzrw[(size_t)t * 2048 + di] = g;   // yg in xp half (lda=2048 downstream)
        }
    }
}

// ---------------- launcher ----------------
extern "C" void kernel_launch(void* const* d_in, const int* in_sizes, int n_in,
                              void* d_out, int out_size, void* d_ws, size_t ws_size,
                              hipStream_t stream)
{
    (void)in_sizes; (void)n_in;
    if (ws_size < WS_NEEDED) {
        zero_out_kernel<<<(out_size + 255) / 256, 256, 0, stream>>>((float*)d_out, out_size);
        return;
    }
    const float* x     = (const float*)d_in[0];
    const float* w_in  = (const float*)d_in[1];
    const float* cw    = (const float*)d_in[2];
    const float* cb    = (const float*)d_in[3];
    const float* w_xp  = (const float*)d_in[4];
    const float* w_dt  = (const float*)d_in[5];
    const float* b_dt  = (const float*)d_in[6];
    const float* A_log = (const float*)d_in[7];
    const float* A_img = (const float*)d_in[8];
    const float* Dp    = (const float*)d_in[9];
    const float* w_out = (const float*)d_in[10];

    char* ws = (char*)d_ws;
    float* xz    = (float*)(ws + OFF_XZ);
    float* xc    = (float*)(ws + OFF_XC);
    float* proj  = (float*)(ws + OFF_PROJ);
    float* delta = (float*)(ws + OFF_DELTA);
    float* gl    = (float*)(ws + OFF_GL);
    float* ge    = (float*)(ws + OFF_GE);
    float* summ  = (float*)(ws + OFF_SUMM);
    float* out   = (float*)d_out;

    // 1. xz = x @ in_proj_w^T   (M=2048, N=2048, K=512)
    gemm_f32<<<dim3(32, 32), 256, 0, stream>>>(x, w_in, xz, 2048, 2048, 512, 512, 2048);
    // 2. causal conv + silu
    conv_silu_kernel<<<8192, 256, 0, stream>>>(xz, cw, cb, xc);
    // 3. proj = xc @ x_proj_w^T (M=2048, N=560, K=1024)
    gemm_f32<<<dim3(9, 32), 256, 0, stream>>>(xc, w_xp, proj, 2048, 560, 1024, 1024, 560);
    // 4. delta + gates
    dt_kernel<<<dim3(2048, 4), 256, 0, stream>>>(proj, w_dt, b_dt, delta, gl, ge);
    // 5-7. chunked complex scan; pass2 writes yg into xz's first half
    scan_pass1<<<1024, 512, 0, stream>>>(delta, xc, proj, gl, ge, A_log, A_img, summ);
    scan_combine<<<128, 256, 0, stream>>>(summ);
    scan_pass2<<<1024, 512, 0, stream>>>(delta, xc, proj, gl, ge, A_log, A_img,
                                         Dp, xz, summ);
    // 8. out = yg @ out_proj_w^T (M=2048, N=512, K=1024, A=xz first half, lda=2048)
    gemm_f32<<<dim3(8, 32), 256, 0, stream>>>(xz, w_out, out, 2048, 512, 1024, 2048, 512);
}